// Round 1
// baseline (321.633 us; speedup 1.0000x reference)
//
#include <hip/hip_runtime.h>
#include <math.h>

// Problem dims (hardcoded from reference):
//   B=16, C=256, H=W=128
#define BATCHES      16
#define CHANNELS     256
#define HW           (128 * 128)                 // 16384
#define PER_BATCH    (CHANNELS * HW)             // 4,194,304 floats per (input,batch)
#define VEC_PER_BATCH (PER_BATCH / 4)            // 1,048,576 float4
#define BLOCKS_PER_BN 64
#define RTHREADS      256
#define VEC_PER_THREAD (VEC_PER_BATCH / (BLOCKS_PER_BN * RTHREADS)) // 64

// ws layout (floats): [0 .. 3071] partials (3 inputs * 16 batches * 64 blocks)
//                     [3072 .. 3119] attention scalars (3*16)
#define PARTIALS_OFF 0
#define ATT_OFF      (3 * BATCHES * BLOCKS_PER_BN)

// ---------------------------------------------------------------------------
// Kernel 1: per-block weighted partial sums.
// grid.x = 3 * 16 * 64.  blk = which*16*64 + batch*64 + chunk.
// Each block covers a contiguous 16384-float4 slice of one (input,batch).
// ---------------------------------------------------------------------------
__global__ __launch_bounds__(RTHREADS) void fusion_reduce_kernel(
    const float* __restrict__ gray,
    const float* __restrict__ green,
    const float* __restrict__ rgb,
    const float* __restrict__ conv_w,
    float* __restrict__ partials)
{
    int blk   = blockIdx.x;
    int chunk = blk & (BLOCKS_PER_BN - 1);
    int bn    = blk >> 6;                 // which*16 + batch
    int batch = bn & (BATCHES - 1);
    int which = bn >> 4;

    const float* x = (which == 0) ? gray : (which == 1) ? green : rgb;
    const float4* xv = reinterpret_cast<const float4*>(x) +
                       (size_t)batch * VEC_PER_BATCH;

    __shared__ float sw[CHANNELS];
    for (int i = threadIdx.x; i < CHANNELS; i += RTHREADS) sw[i] = conv_w[i];
    __syncthreads();

    float sum = 0.0f;
    int base = chunk * (RTHREADS * VEC_PER_THREAD);
    #pragma unroll 4
    for (int i = 0; i < VEC_PER_THREAD; ++i) {
        int v = base + i * RTHREADS + (int)threadIdx.x;
        float4 d = xv[v];
        // channel = element_idx / 16384 = (4*v) / 16384 = v >> 12 (all 4 same ch)
        float wc = sw[v >> 12];
        sum += (d.x + d.y + d.z + d.w) * wc;
    }

    // wave64 tree reduce
    #pragma unroll
    for (int off = 32; off > 0; off >>= 1) sum += __shfl_down(sum, off, 64);

    __shared__ float s4[RTHREADS / 64];
    int wid = threadIdx.x >> 6;
    if ((threadIdx.x & 63) == 0) s4[wid] = sum;
    __syncthreads();
    if (threadIdx.x == 0) {
        float t = s4[0] + s4[1] + s4[2] + s4[3];
        partials[blk] = t;
    }
}

// ---------------------------------------------------------------------------
// Kernel 2: reduce 64 partials per (input,batch) -> sigmoid attention scalar.
// grid.x = 48, block = 64.
// ---------------------------------------------------------------------------
__global__ __launch_bounds__(64) void fusion_att_kernel(
    const float* __restrict__ partials,
    const float* __restrict__ conv_b,
    float* __restrict__ att)
{
    int row = blockIdx.x;                  // which*16 + batch
    float v = partials[row * BLOCKS_PER_BN + (int)threadIdx.x];
    #pragma unroll
    for (int off = 32; off > 0; off >>= 1) v += __shfl_down(v, off, 64);
    if (threadIdx.x == 0) {
        float logit = v * (1.0f / (float)HW) + conv_b[0];
        att[row] = 1.0f / (1.0f + expf(-logit));
    }
}

// ---------------------------------------------------------------------------
// Kernel 3: apply attention and fuse.
// out = gray*a_g + 10*(green*a_gr + rgb*a_r), float4 granularity.
// grid.x = 16*2^20 / 256 = 65536 blocks of 256 threads, 1 float4 each.
// ---------------------------------------------------------------------------
__global__ __launch_bounds__(RTHREADS) void fusion_apply_kernel(
    const float4* __restrict__ gray,
    const float4* __restrict__ green,
    const float4* __restrict__ rgb,
    const float* __restrict__ att,
    float4* __restrict__ out)
{
    size_t i = (size_t)blockIdx.x * RTHREADS + threadIdx.x;
    int b = (int)(i >> 20);                // VEC_PER_BATCH = 2^20
    float ag  = att[b];
    float agr = att[BATCHES + b];
    float ar  = att[2 * BATCHES + b];

    float4 dg = gray[i], dn = green[i], dr = rgb[i];
    float4 o;
    o.x = dg.x * ag + 10.0f * (dn.x * agr + dr.x * ar);
    o.y = dg.y * ag + 10.0f * (dn.y * agr + dr.y * ar);
    o.z = dg.z * ag + 10.0f * (dn.z * agr + dr.z * ar);
    o.w = dg.w * ag + 10.0f * (dn.w * agr + dr.w * ar);
    out[i] = o;
}

extern "C" void kernel_launch(void* const* d_in, const int* in_sizes, int n_in,
                              void* d_out, int out_size, void* d_ws, size_t ws_size,
                              hipStream_t stream) {
    const float* gray   = (const float*)d_in[0];
    const float* green  = (const float*)d_in[1];
    const float* rgb    = (const float*)d_in[2];
    const float* conv_w = (const float*)d_in[3];
    const float* conv_b = (const float*)d_in[4];
    float* out = (float*)d_out;
    float* ws  = (float*)d_ws;

    float* partials = ws + PARTIALS_OFF;   // 3072 floats
    float* att      = ws + ATT_OFF;        // 48 floats

    // Pass 1: weighted partial sums (reads all 3 inputs once)
    fusion_reduce_kernel<<<3 * BATCHES * BLOCKS_PER_BN, RTHREADS, 0, stream>>>(
        gray, green, rgb, conv_w, partials);

    // Pass 2: finish reduction + sigmoid (48 scalars)
    fusion_att_kernel<<<3 * BATCHES, 64, 0, stream>>>(partials, conv_b, att);

    // Pass 3: apply + fuse (reads all 3 inputs again, writes output)
    int total_vec = BATCHES * VEC_PER_BATCH;     // 16,777,216
    fusion_apply_kernel<<<total_vec / RTHREADS, RTHREADS, 0, stream>>>(
        (const float4*)gray, (const float4*)green, (const float4*)rgb,
        att, (float4*)out);
}